// Round 1
// baseline (844.985 us; speedup 1.0000x reference)
//
#include <hip/hip_runtime.h>

#define EMBED_D   2048
#define N_EXP     64
#define K_TOP     8
#define BK        64
#define TOK_BLK   64
#define THREADS   512          // 8 waves = 8 expert-groups, each full-k
#define EPW       8            // experts per wave
#define XS_STRIDE 65           // 65 mod 32 = 1 -> conflict-free column reads
#define NCHUNK    (EMBED_D / BK)   // 32

__global__ __launch_bounds__(THREADS, 4) void moe_gate_main(
    const float* __restrict__ X,   // [n_tok][2048]
    const float* __restrict__ W,   // [64][2048]
    float* __restrict__ out,       // [n_tok*8 idx][n_tok*8 w][1 aux]
    float* __restrict__ ws,        // [64 counts][64 score sums]
    int n_tok)
{
    // LDS: 35.8 KB total
    __shared__ float xs[BK][XS_STRIDE];           // 16640 B  X tile [k][tok]
    __shared__ float Lp[TOK_BLK][N_EXP + 1];      // 16640 B  logits [tok][exp]
    __shared__ float sInvZ[TOK_BLK];
    __shared__ float sCnt[N_EXP];
    __shared__ float sColp[8][N_EXP];

    const int tid  = threadIdx.x;
    const int lane = tid & 63;                     // token within tile
    const int wv   = __builtin_amdgcn_readfirstlane(tid >> 6);  // 0..7
    const int e0   = wv * EPW;                     // this wave's 8 experts
    const int t0   = blockIdx.x * TOK_BLK;

    float acc[EPW];
#pragma unroll
    for (int j = 0; j < EPW; ++j) acc[j] = 0.f;

    // staging: 64 tok x 64 k = 1024 float4; 512 threads -> 2 float4 each
    const int m0 = tid >> 4, kq = tid & 15;
    const int m1 = 32 + m0;
    const float* xr0 = X + (size_t)(t0 + m0) * EMBED_D + (kq << 2);
    const float* xr1 = X + (size_t)(t0 + m1) * EMBED_D + (kq << 2);
    float4 p0 = *(const float4*)xr0;
    float4 p1 = *(const float4*)xr1;

    // Opaque per-lane zero: forces W accesses onto the VECTOR memory path
    // (global_load_dwordx4, uniform addr -> 1 coalesced L1 req, broadcast).
    // The previous s_load path serialized on the scalar cache's miss pipe
    // and forced lgkmcnt(0) drains against the ds_read x-values.
    int vz;
    asm volatile("v_mov_b32 %0, 0" : "=v"(vz));
    const float* wb = W + e0 * EMBED_D + vz;

    for (int c = 0; c < NCHUNK; ++c) {
        __syncthreads();   // previous chunk's compute done -> xs writable
#pragma unroll
        for (int j = 0; j < 4; ++j) {
            xs[kq * 4 + j][m0] = ((const float*)&p0)[j];
            xs[kq * 4 + j][m1] = ((const float*)&p1)[j];
        }
        if (c + 1 < NCHUNK) {   // register prefetch of next X chunk
            p0 = *(const float4*)(xr0 + (c + 1) * BK);
            p1 = *(const float4*)(xr1 + (c + 1) * BK);
        }
        __syncthreads();   // xs ready

        const float* wp = wb + c * BK;   // this chunk's W slice (vector path)

        // 2-stage register pipeline on W: load kk+1 while FMA-ing kk.
        float4 wc[EPW], wn[EPW];
#pragma unroll
        for (int j = 0; j < EPW; ++j)
            wc[j] = *(const float4*)(wp + j * EMBED_D);

#pragma unroll
        for (int kk = 0; kk < 16; ++kk) {
            if (kk < 15) {
#pragma unroll
                for (int j = 0; j < EPW; ++j)
                    wn[j] = *(const float4*)(wp + j * EMBED_D + (kk + 1) * 4);
            }
#pragma unroll
            for (int k4 = 0; k4 < 4; ++k4) {
                const float x = xs[kk * 4 + k4][lane];
#pragma unroll
                for (int j = 0; j < EPW; ++j)
                    acc[j] = fmaf(x, ((const float*)&wc[j])[k4], acc[j]);
            }
            if (kk < 15) {
#pragma unroll
                for (int j = 0; j < EPW; ++j)
                    wc[j] = wn[j];
            }
        }
    }

    // scatter logits: addr = lane*65 + e -> conflict-free across lanes
#pragma unroll
    for (int j = 0; j < EPW; ++j)
        Lp[lane][e0 + j] = acc[j];
    if (tid < N_EXP) sCnt[tid] = 0.f;
    __syncthreads();

    // per-token: softmax, top-8 (threads 0..63)
    if (tid < TOK_BLK) {
        const int t = tid;
        float mx = -1e30f;
        for (int e = 0; e < N_EXP; ++e)
            mx = fmaxf(mx, Lp[t][e]);
        float Z = 0.f;
        float tv[K_TOP]; int ti[K_TOP];
#pragma unroll
        for (int j = 0; j < K_TOP; ++j) { tv[j] = -1e30f; ti[j] = 0; }
        for (int e = 0; e < N_EXP; ++e) {
            const float s = __expf(Lp[t][e] - mx);
            Lp[t][e] = s;                 // unnormalized score for Pi pass
            Z += s;
            float v = s; int id = e;
#pragma unroll
            for (int j = 0; j < K_TOP; ++j) {  // strict > : ties keep lower idx
                if (v > tv[j]) {
                    float fv = tv[j]; tv[j] = v; v = fv;
                    int   fi = ti[j]; ti[j] = id; id = fi;
                }
            }
        }
        const float invZ = 1.0f / Z;
        sInvZ[t] = invZ;
        const size_t ob = (size_t)(t0 + t) * K_TOP;
        const size_t wo = (size_t)n_tok * K_TOP;
#pragma unroll
        for (int j = 0; j < K_TOP; ++j) {
            out[ob + j]      = (float)ti[j];
            out[wo + ob + j] = tv[j] * invZ;
            atomicAdd(&sCnt[ti[j]], 1.0f);
        }
    }
    __syncthreads();

    // per-expert score sums (Pi numerator): 8 groups x 8 tokens
    {
        const int e = tid & 63, g = tid >> 6;
        float s = 0.f;
#pragma unroll
        for (int i = 0; i < 8; ++i) {
            const int t = g * 8 + i;
            s += Lp[t][e] * sInvZ[t];
        }
        sColp[g][e] = s;
    }
    __syncthreads();
    if (tid < N_EXP) {
        float s = 0.f;
#pragma unroll
        for (int g = 0; g < 8; ++g) s += sColp[g][tid];
        atomicAdd(&ws[64 + tid], s);
        atomicAdd(&ws[tid], sCnt[tid]);
    }
}

__global__ void moe_aux(const float* __restrict__ ws, float* __restrict__ out, int n_tok)
{
    const int e = threadIdx.x;   // 64 threads
    const float counts = ws[e];
    const float ssum   = ws[64 + e];
    const float Pi = ssum / (float)n_tok;
    const float ce = counts / ((float)n_tok * (float)K_TOP);
    float term = Pi * ce * (float)N_EXP;
    for (int off = 32; off; off >>= 1) term += __shfl_down(term, off);
    if (e == 0) out[(size_t)2 * n_tok * K_TOP] = term * 0.01f;
}

extern "C" void kernel_launch(void* const* d_in, const int* in_sizes, int n_in,
                              void* d_out, int out_size, void* d_ws, size_t ws_size,
                              hipStream_t stream)
{
    const float* X = (const float*)d_in[0];
    const float* W = (const float*)d_in[1];
    float* out = (float*)d_out;
    float* ws  = (float*)d_ws;
    const int n_tok = in_sizes[0] / EMBED_D;   // 32768

    hipMemsetAsync(ws, 0, 2 * N_EXP * sizeof(float), stream);
    moe_gate_main<<<n_tok / TOK_BLK, THREADS, 0, stream>>>(X, W, out, ws, n_tok);
    moe_aux<<<1, 64, 0, stream>>>(ws, out, n_tok);
}

// Round 2
// 571.945 us; speedup vs baseline: 1.4774x; 1.4774x over previous
//
#include <hip/hip_runtime.h>

#define EMBED_D 2048
#define N_EXP   64
#define K_TOP   8
#define TOK_BLK 64
#define THREADS 256              // 4 waves; wave w owns tokens [w*16, w*16+16)
#define NKSTEP  (EMBED_D / 32)   // 64 K-steps of 32

typedef __attribute__((ext_vector_type(8))) short bf16x8;   // 8 bf16 = 4 VGPR
typedef __attribute__((ext_vector_type(4))) float f32x4;    // MFMA C/D

__device__ __forceinline__ uint bf16_rne(float x) {
    uint u = __float_as_uint(x);
    return (u + 0x7fffu + ((u >> 16) & 1u)) >> 16;   // round-to-nearest-even
}
__device__ __forceinline__ float bf16f(uint h) { return __uint_as_float(h << 16); }

// W[64][2048] fp32 -> three bf16 planes (h/m/l), row-major [64][2048].
// 64 blocks x 256 threads x 8 elements.
__global__ void w_prep(const float* __restrict__ W, ushort* __restrict__ WH,
                       ushort* __restrict__ WM, ushort* __restrict__ WL)
{
    const int gid = blockIdx.x * 256 + threadIdx.x;
    const float4 a = ((const float4*)W)[gid * 2];
    const float4 b = ((const float4*)W)[gid * 2 + 1];
    const float e[8] = {a.x, a.y, a.z, a.w, b.x, b.y, b.z, b.w};
    ushort h[8], m[8], l[8];
#pragma unroll
    for (int j = 0; j < 8; ++j) {
        const uint hh = bf16_rne(e[j]);
        const float r1 = e[j] - bf16f(hh);
        const uint mm = bf16_rne(r1);
        const uint ll = bf16_rne(r1 - bf16f(mm));
        h[j] = (ushort)hh; m[j] = (ushort)mm; l[j] = (ushort)ll;
    }
    ushort4* H = (ushort4*)(WH + (size_t)gid * 8);
    ushort4* M = (ushort4*)(WM + (size_t)gid * 8);
    ushort4* L = (ushort4*)(WL + (size_t)gid * 8);
    H[0] = make_ushort4(h[0], h[1], h[2], h[3]); H[1] = make_ushort4(h[4], h[5], h[6], h[7]);
    M[0] = make_ushort4(m[0], m[1], m[2], m[3]); M[1] = make_ushort4(m[4], m[5], m[6], m[7]);
    L[0] = make_ushort4(l[0], l[1], l[2], l[3]); L[1] = make_ushort4(l[4], l[5], l[6], l[7]);
}

__global__ __launch_bounds__(THREADS, 2) void moe_gate_main(
    const float*  __restrict__ X,    // [n_tok][2048] fp32
    const ushort* __restrict__ WH,   // [64][2048] bf16 hi
    const ushort* __restrict__ WM,   // [64][2048] bf16 mid
    const ushort* __restrict__ WL,   // [64][2048] bf16 lo
    float* __restrict__ out,
    float* __restrict__ ws,
    int n_tok)
{
    __shared__ float Lp[TOK_BLK][N_EXP + 1];   // logits [tok][exp], stride 65
    __shared__ float sInvZ[TOK_BLK];
    __shared__ float sCnt[N_EXP];
    __shared__ float sColp[4][N_EXP];

    const int tid  = threadIdx.x;
    const int lane = tid & 63;
    const int wv   = tid >> 6;        // 0..3
    const int row  = lane & 15;       // A: token-in-16; B: expert-in-16
    const int g    = lane >> 4;       // k-subgroup: slot j <-> k0 + 8g + j
    const int t0   = blockIdx.x * TOK_BLK;

    const int tok = t0 + wv * 16 + row;
    const float* xp = X + (size_t)tok * EMBED_D + g * 8;

    const size_t woff = (size_t)row * EMBED_D + g * 8;
    const ushort* wh = WH + woff;
    const ushort* wm = WM + woff;
    const ushort* wl = WL + woff;

    f32x4 acc[4];
#pragma unroll
    for (int n = 0; n < 4; ++n) acc[n] = (f32x4){0.f, 0.f, 0.f, 0.f};

    // 2-deep X register prefetch (32 B/lane per step -> 4 KB/wave in flight)
    float4 q0 = *(const float4*)(xp);
    float4 q1 = *(const float4*)(xp + 4);
    float4 r0 = *(const float4*)(xp + 32);
    float4 r1 = *(const float4*)(xp + 36);

    for (int kk = 0; kk < NKSTEP; ++kk) {
        float4 p0 = {0, 0, 0, 0}, p1 = {0, 0, 0, 0};
        if (kk + 2 < NKSTEP) {                       // wave-uniform guard
            p0 = *(const float4*)(xp + (kk + 2) * 32);
            p1 = *(const float4*)(xp + (kk + 2) * 32 + 4);
        }

        // split current X into h/m/l bf16 fragments (exact to 2^-27 rel)
        bf16x8 ah, am, al;
        {
            const float e[8] = {q0.x, q0.y, q0.z, q0.w, q1.x, q1.y, q1.z, q1.w};
#pragma unroll
            for (int j = 0; j < 8; ++j) {
                const uint h = bf16_rne(e[j]);
                const float r = e[j] - bf16f(h);
                const uint m = bf16_rne(r);
                const uint l = bf16_rne(r - bf16f(m));
                ah[j] = (short)h; am[j] = (short)m; al[j] = (short)l;
            }
        }

        const size_t kofs = (size_t)kk * 32;
#pragma unroll
        for (int n = 0; n < 4; ++n) {
            const size_t o = (size_t)(n * 16) * EMBED_D + kofs;
            const bf16x8 bh = *(const bf16x8*)(wh + o);
            const bf16x8 bm = *(const bf16x8*)(wm + o);
            const bf16x8 bl = *(const bf16x8*)(wl + o);
            // 6 significant cross-products of (h+m+l)*(H+M+L)
            acc[n] = __builtin_amdgcn_mfma_f32_16x16x32_bf16(ah, bh, acc[n], 0, 0, 0);
            acc[n] = __builtin_amdgcn_mfma_f32_16x16x32_bf16(am, bh, acc[n], 0, 0, 0);
            acc[n] = __builtin_amdgcn_mfma_f32_16x16x32_bf16(ah, bm, acc[n], 0, 0, 0);
            acc[n] = __builtin_amdgcn_mfma_f32_16x16x32_bf16(al, bh, acc[n], 0, 0, 0);
            acc[n] = __builtin_amdgcn_mfma_f32_16x16x32_bf16(ah, bl, acc[n], 0, 0, 0);
            acc[n] = __builtin_amdgcn_mfma_f32_16x16x32_bf16(am, bm, acc[n], 0, 0, 0);
        }

        q0 = r0; q1 = r1; r0 = p0; r1 = p1;
    }

    // C/D layout (m89/m91): col = lane&15 (expert), row = (lane>>4)*4 + reg (token)
#pragma unroll
    for (int n = 0; n < 4; ++n)
#pragma unroll
        for (int r = 0; r < 4; ++r)
            Lp[wv * 16 + g * 4 + r][n * 16 + row] = acc[n][r];
    if (tid < N_EXP) sCnt[tid] = 0.f;
    __syncthreads();

    // per-token softmax + top-8 (threads 0..63, one token each)
    if (tid < TOK_BLK) {
        const int t = tid;
        float mx = -1e30f;
        for (int e = 0; e < N_EXP; ++e)
            mx = fmaxf(mx, Lp[t][e]);
        float Z = 0.f;
        float tv[K_TOP]; int ti[K_TOP];
#pragma unroll
        for (int j = 0; j < K_TOP; ++j) { tv[j] = -1e30f; ti[j] = 0; }
        for (int e = 0; e < N_EXP; ++e) {
            const float s = __expf(Lp[t][e] - mx);
            Lp[t][e] = s;                 // unnormalized score for Pi pass
            Z += s;
            float v = s; int id = e;
#pragma unroll
            for (int j = 0; j < K_TOP; ++j) {  // strict > : ties keep lower idx
                if (v > tv[j]) {
                    float fv = tv[j]; tv[j] = v; v = fv;
                    int   fi = ti[j]; ti[j] = id; id = fi;
                }
            }
        }
        const float invZ = 1.0f / Z;
        sInvZ[t] = invZ;
        const size_t ob = (size_t)(t0 + t) * K_TOP;
        const size_t wo = (size_t)n_tok * K_TOP;
#pragma unroll
        for (int j = 0; j < K_TOP; ++j) {
            out[ob + j]      = (float)ti[j];
            out[wo + ob + j] = tv[j] * invZ;
            atomicAdd(&sCnt[ti[j]], 1.0f);
        }
    }
    __syncthreads();

    // per-expert score sums (Pi numerator): 4 groups x 16 tokens
    {
        const int e = tid & 63, g2 = tid >> 6;
        float s = 0.f;
#pragma unroll
        for (int i = 0; i < 16; ++i) {
            const int t = g2 * 16 + i;
            s += Lp[t][e] * sInvZ[t];
        }
        sColp[g2][e] = s;
    }
    __syncthreads();
    if (tid < N_EXP) {
        float s = 0.f;
#pragma unroll
        for (int g2 = 0; g2 < 4; ++g2) s += sColp[g2][tid];
        atomicAdd(&ws[64 + tid], s);
        atomicAdd(&ws[tid], sCnt[tid]);
    }
}

__global__ void moe_aux(const float* __restrict__ ws, float* __restrict__ out, int n_tok)
{
    const int e = threadIdx.x;   // 64 threads
    const float counts = ws[e];
    const float ssum   = ws[64 + e];
    const float Pi = ssum / (float)n_tok;
    const float ce = counts / ((float)n_tok * (float)K_TOP);
    float term = Pi * ce * (float)N_EXP;
    for (int off = 32; off; off >>= 1) term += __shfl_down(term, off);
    if (e == 0) out[(size_t)2 * n_tok * K_TOP] = term * 0.01f;
}

extern "C" void kernel_launch(void* const* d_in, const int* in_sizes, int n_in,
                              void* d_out, int out_size, void* d_ws, size_t ws_size,
                              hipStream_t stream)
{
    const float* X = (const float*)d_in[0];
    const float* W = (const float*)d_in[1];
    float* out = (float*)d_out;
    float* ws  = (float*)d_ws;
    const int n_tok = in_sizes[0] / EMBED_D;   // 32768

    // workspace layout: [0..127] counters | +256 floats: WH | WM | WL (bf16 planes)
    // needs 1 KB + 3*64*2048*2 B = 769 KB of workspace
    ushort* WH = (ushort*)(ws + 256);
    ushort* WM = WH + (size_t)N_EXP * EMBED_D;
    ushort* WL = WM + (size_t)N_EXP * EMBED_D;

    hipMemsetAsync(ws, 0, 2 * N_EXP * sizeof(float), stream);
    w_prep<<<64, 256, 0, stream>>>(W, WH, WM, WL);
    moe_gate_main<<<n_tok / TOK_BLK, THREADS, 0, stream>>>(X, WH, WM, WL, out, ws, n_tok);
    moe_aux<<<1, 64, 0, stream>>>(ws, out, n_tok);
}

// Round 3
// 407.785 us; speedup vs baseline: 2.0721x; 1.4026x over previous
//
#include <hip/hip_runtime.h>

#define EMBED_D 2048
#define N_EXP   64
#define K_TOP   8
#define TOK_BLK 64
#define THREADS 512
#define NCHUNK  32            // K chunks of 64
#define CHUNK_B 24576         // W-frag bytes/chunk: 3 planes * 2 kk * 4 n * 64 lanes * 16 B

typedef __attribute__((ext_vector_type(8))) short bf16x8;   // 8 bf16 = 4 VGPR
typedef __attribute__((ext_vector_type(4))) float f32x4;    // MFMA C/D

__device__ __forceinline__ uint bf16_rne(float x) {
    uint u = __float_as_uint(x);
    return (u + 0x7fffu + ((u >> 16) & 1u)) >> 16;   // round-to-nearest-even
}
__device__ __forceinline__ float bf16f(uint h) { return __uint_as_float(h << 16); }

// direct global->LDS, 16 B per lane; LDS dest = uniform base + lane*16
__device__ __forceinline__ void stage16(const void* g, void* l)
{
    typedef __attribute__((address_space(1))) const unsigned int gu32;
    typedef __attribute__((address_space(3))) unsigned int lu32;
    __builtin_amdgcn_global_load_lds((gu32*)g, (lu32*)l, 16, 0, 0);
}

// W[64][2048] fp32 -> fragment-major h/m/l bf16 planes in workspace.
// Byte layout: chunk c (K=64) | ((p*2+kk)*4+n)*1024 | lane*16 | j*2
// where expert e = n*16+row, k = c*64+kk*32+g*8+j, lane = g*16+row.
__global__ void w_prep(const float* __restrict__ W, ushort* __restrict__ WF)
{
    const int e = blockIdx.x;       // expert 0..63
    const int t = threadIdx.x;      // 0..255, 8 consecutive k each
    const float4 a = *(const float4*)(W + (size_t)e * EMBED_D + t * 8);
    const float4 b = *(const float4*)(W + (size_t)e * EMBED_D + t * 8 + 4);
    const float ev[8] = {a.x, a.y, a.z, a.w, b.x, b.y, b.z, b.w};
    ushort h[8], m[8], l[8];
#pragma unroll
    for (int j = 0; j < 8; ++j) {
        const uint hh = bf16_rne(ev[j]);
        const float r1 = ev[j] - bf16f(hh);
        const uint mm = bf16_rne(r1);
        const uint ll = bf16_rne(r1 - bf16f(mm));
        h[j] = (ushort)hh; m[j] = (ushort)mm; l[j] = (ushort)ll;
    }
    const int c  = t >> 3;
    const int kk = (t >> 2) & 1;
    const int g  = t & 3;
    const int lane = g * 16 + (e & 15);
    const int n    = e >> 4;
    // ushort offsets: c*12288 + p*4096 + kk*2048 + n*512 + lane*8
    const size_t base = (size_t)c * 12288 + (size_t)kk * 2048 + (size_t)n * 512 + (size_t)lane * 8;
    ushort4* H = (ushort4*)(WF + base);
    ushort4* M = (ushort4*)(WF + base + 4096);
    ushort4* L = (ushort4*)(WF + base + 8192);
    H[0] = make_ushort4(h[0], h[1], h[2], h[3]); H[1] = make_ushort4(h[4], h[5], h[6], h[7]);
    M[0] = make_ushort4(m[0], m[1], m[2], m[3]); M[1] = make_ushort4(m[4], m[5], m[6], m[7]);
    L[0] = make_ushort4(l[0], l[1], l[2], l[3]); L[1] = make_ushort4(l[4], l[5], l[6], l[7]);
}

__global__ __launch_bounds__(THREADS, 4) void moe_gate_main(
    const float*  __restrict__ X,    // [n_tok][2048] fp32
    const ushort* __restrict__ WF,   // fragment-major W planes (768 KB)
    float* __restrict__ out,
    float* __restrict__ ws,
    int n_tok)
{
    // 48 KB: double-buffered W fragments during the loop; reused as Lp after.
    __shared__ __align__(16) char smem[2 * CHUNK_B];
    __shared__ float sInvZ[TOK_BLK];
    __shared__ float sCnt[N_EXP];
    __shared__ float sColp[8][N_EXP];

    const int tid  = threadIdx.x;
    const int lane = tid & 63;
    const int wv   = __builtin_amdgcn_readfirstlane(tid >> 6);  // 0..7
    const int tg   = wv & 3;      // token group (16 tokens)
    const int eh   = wv >> 2;     // expert half (32 experts)
    const int row  = lane & 15;
    const int g    = lane >> 4;
    const int t0   = blockIdx.x * TOK_BLK;
    const int tok  = t0 + tg * 16 + row;

    const float* xp = X + (size_t)tok * EMBED_D + g * 8;
    const char*  wf = (const char*)WF;

    f32x4 acc[2];
    acc[0] = (f32x4){0.f, 0.f, 0.f, 0.f};
    acc[1] = (f32x4){0.f, 0.f, 0.f, 0.f};

    // X registers for the current chunk (16 floats/lane)
    float4 xq[4];
#pragma unroll
    for (int i = 0; i < 2; ++i) {
        xq[2 * i]     = *(const float4*)(xp + i * 32);
        xq[2 * i + 1] = *(const float4*)(xp + i * 32 + 4);
    }

    // stage W chunk 0 into buffer 0 (each wave stages 3 KB)
    {
        const char* gs = wf + (size_t)wv * 3072 + lane * 16;
        char* ld = smem + wv * 3072;
#pragma unroll
        for (int i = 0; i < 3; ++i)
            stage16(gs + i * 1024, ld + i * 1024);
    }
    __syncthreads();   // implicit vmcnt(0): chunk 0 staged, X arrived

    for (int c = 0; c < NCHUNK; ++c) {
        const int cur = c & 1;

        // (1) issue next W chunk staging (drained by this iteration's barrier)
        if (c + 1 < NCHUNK) {
            const char* gs = wf + (size_t)(c + 1) * CHUNK_B + wv * 3072 + lane * 16;
            char* ld = smem + (cur ^ 1) * CHUNK_B + wv * 3072;
#pragma unroll
            for (int i = 0; i < 3; ++i)
                stage16(gs + i * 1024, ld + i * 1024);
        }

        // (2) split current X into h/m/l bf16 fragments (both kk steps)
        bf16x8 ah[2], am[2], al[2];
#pragma unroll
        for (int kk = 0; kk < 2; ++kk) {
            const float ev[8] = {xq[2*kk].x, xq[2*kk].y, xq[2*kk].z, xq[2*kk].w,
                                 xq[2*kk+1].x, xq[2*kk+1].y, xq[2*kk+1].z, xq[2*kk+1].w};
#pragma unroll
            for (int j = 0; j < 8; ++j) {
                const uint h  = bf16_rne(ev[j]);
                const float r1 = ev[j] - bf16f(h);
                const uint m  = bf16_rne(r1);
                const uint l  = bf16_rne(r1 - bf16f(m));
                ah[kk][j] = (short)h; am[kk][j] = (short)m; al[kk][j] = (short)l;
            }
        }

        // (3) issue next chunk's X loads (xq now dead; full chunk to cover latency)
        if (c + 1 < NCHUNK) {
#pragma unroll
            for (int i = 0; i < 2; ++i) {
                xq[2 * i]     = *(const float4*)(xp + (c + 1) * 64 + i * 32);
                xq[2 * i + 1] = *(const float4*)(xp + (c + 1) * 64 + i * 32 + 4);
            }
        }

        // (4) MFMA phase: B fragments from LDS (ds_read_b128, conflict-free)
        const char* wb = smem + cur * CHUNK_B;
#pragma unroll
        for (int kk = 0; kk < 2; ++kk) {
#pragma unroll
            for (int nl = 0; nl < 2; ++nl) {
                const int n = eh * 2 + nl;
                const char* bp = wb + (size_t)(kk * 4 + n) * 1024 + lane * 16;
                const bf16x8 bh = *(const bf16x8*)(bp);            // plane h
                const bf16x8 bm = *(const bf16x8*)(bp + 8192);     // plane m
                const bf16x8 bl = *(const bf16x8*)(bp + 16384);    // plane l
                // same 6-product order as R2 -> bitwise-identical logits
                acc[nl] = __builtin_amdgcn_mfma_f32_16x16x32_bf16(ah[kk], bh, acc[nl], 0, 0, 0);
                acc[nl] = __builtin_amdgcn_mfma_f32_16x16x32_bf16(am[kk], bh, acc[nl], 0, 0, 0);
                acc[nl] = __builtin_amdgcn_mfma_f32_16x16x32_bf16(ah[kk], bm, acc[nl], 0, 0, 0);
                acc[nl] = __builtin_amdgcn_mfma_f32_16x16x32_bf16(al[kk], bh, acc[nl], 0, 0, 0);
                acc[nl] = __builtin_amdgcn_mfma_f32_16x16x32_bf16(ah[kk], bl, acc[nl], 0, 0, 0);
                acc[nl] = __builtin_amdgcn_mfma_f32_16x16x32_bf16(am[kk], bm, acc[nl], 0, 0, 0);
            }
        }
        __syncthreads();   // compute done + next chunk staged (vmcnt(0) drain)
    }

    // W buffers dead -> reuse smem as logits [tok][exp] (stride 65)
    float (*Lp)[N_EXP + 1] = (float (*)[N_EXP + 1])smem;
    // C/D layout: col = lane&15 (expert-in-16), row = g*4 + reg (token-in-16)
#pragma unroll
    for (int nl = 0; nl < 2; ++nl)
#pragma unroll
        for (int r = 0; r < 4; ++r)
            Lp[tg * 16 + g * 4 + r][(eh * 2 + nl) * 16 + row] = acc[nl][r];
    if (tid < N_EXP) sCnt[tid] = 0.f;
    __syncthreads();

    // per-token softmax + top-8 (threads 0..63)
    if (tid < TOK_BLK) {
        const int t = tid;
        float mx = -1e30f;
        for (int e = 0; e < N_EXP; ++e)
            mx = fmaxf(mx, Lp[t][e]);
        float Z = 0.f;
        float tv[K_TOP]; int ti[K_TOP];
#pragma unroll
        for (int j = 0; j < K_TOP; ++j) { tv[j] = -1e30f; ti[j] = 0; }
        for (int e = 0; e < N_EXP; ++e) {
            const float s = __expf(Lp[t][e] - mx);
            Lp[t][e] = s;                 // unnormalized score for Pi pass
            Z += s;
            float v = s; int id = e;
#pragma unroll
            for (int j = 0; j < K_TOP; ++j) {  // strict > : ties keep lower idx
                if (v > tv[j]) {
                    float fv = tv[j]; tv[j] = v; v = fv;
                    int   fi = ti[j]; ti[j] = id; id = fi;
                }
            }
        }
        const float invZ = 1.0f / Z;
        sInvZ[t] = invZ;
        const size_t ob = (size_t)(t0 + t) * K_TOP;
        const size_t wo = (size_t)n_tok * K_TOP;
#pragma unroll
        for (int j = 0; j < K_TOP; ++j) {
            out[ob + j]      = (float)ti[j];
            out[wo + ob + j] = tv[j] * invZ;
            atomicAdd(&sCnt[ti[j]], 1.0f);
        }
    }
    __syncthreads();

    // per-expert score sums (Pi numerator): 8 groups x 8 tokens
    {
        const int e = tid & 63, g2 = tid >> 6;
        float s = 0.f;
#pragma unroll
        for (int i = 0; i < 8; ++i) {
            const int t = g2 * 8 + i;
            s += Lp[t][e] * sInvZ[t];
        }
        sColp[g2][e] = s;
    }
    __syncthreads();
    if (tid < N_EXP) {
        float s = 0.f;
#pragma unroll
        for (int g2 = 0; g2 < 8; ++g2) s += sColp[g2][tid];
        atomicAdd(&ws[64 + tid], s);
        atomicAdd(&ws[tid], sCnt[tid]);
    }
}

__global__ void moe_aux(const float* __restrict__ ws, float* __restrict__ out, int n_tok)
{
    const int e = threadIdx.x;   // 64 threads
    const float counts = ws[e];
    const float ssum   = ws[64 + e];
    const float Pi = ssum / (float)n_tok;
    const float ce = counts / ((float)n_tok * (float)K_TOP);
    float term = Pi * ce * (float)N_EXP;
    for (int off = 32; off; off >>= 1) term += __shfl_down(term, off);
    if (e == 0) out[(size_t)2 * n_tok * K_TOP] = term * 0.01f;
}

extern "C" void kernel_launch(void* const* d_in, const int* in_sizes, int n_in,
                              void* d_out, int out_size, void* d_ws, size_t ws_size,
                              hipStream_t stream)
{
    const float* X = (const float*)d_in[0];
    const float* W = (const float*)d_in[1];
    float* out = (float*)d_out;
    float* ws  = (float*)d_ws;
    const int n_tok = in_sizes[0] / EMBED_D;   // 32768

    // workspace: [0..255] floats counters | fragment-major W planes (768 KB)
    ushort* WF = (ushort*)(ws + 256);

    hipMemsetAsync(ws, 0, 2 * N_EXP * sizeof(float), stream);
    w_prep<<<N_EXP, 256, 0, stream>>>(W, WF);
    moe_gate_main<<<n_tok / TOK_BLK, THREADS, 0, stream>>>(X, WF, out, ws, n_tok);
    moe_aux<<<1, 64, 0, stream>>>(ws, out, n_tok);
}